// Round 1
// baseline (502.652 us; speedup 1.0000x reference)
//
#include <hip/hip_runtime.h>

#define NPTS 131072
// transposed feature region offsets (elements, fp32) in ws feature area:
//   scale0: 56*56*64 = 200704, scale1: 28*28*128 = 100352,
//   scale2: 14*14*256 = 50176, scale3: 7*7*512 = 25088  -> total 376320
#define FT_TOTAL 376320

// native clang vector type — required by __builtin_nontemporal_store
typedef float f32x4 __attribute__((ext_vector_type(4)));

// ------------------------------------------------------------------
// Kernel 1 (fused prep): blocks [0,512) compute per-point projection
// indices (numerics IDENTICAL to the verified absmax==0.0 version);
// blocks [512,1982) transpose feat[b] [C,H,W] -> [H*W, C] so the
// per-point channel gather is contiguous. Both halves are independent
// and exact multiples of 256 threads (131072 = 512*256, 376320 =
// 1470*256) -> no tail checks, block-uniform branch, runs concurrently
// in ONE launch (was two serialized launches).
// ------------------------------------------------------------------
__global__ __launch_bounds__(256) void k_prep(
    const float* __restrict__ pts,
    int4* __restrict__ idx4,
    const float* __restrict__ f0,
    const float* __restrict__ f1,
    const float* __restrict__ f2,
    const float* __restrict__ f3,
    const int* __restrict__ batch,
    float* __restrict__ ft)
{
    int blk = blockIdx.x;
    if (blk < 512) {
        // ---- projection indices ----
        int n = blk * 256 + threadIdx.x;
        float px = pts[3 * n + 0];
        float py = pts[3 * n + 1];
        float pz = pts[3 * n + 2];
        float qh = __fdiv_rn(py, pz);
        float qw = __fdiv_rn(px, -pz);
        float h = __fadd_rn(__fmul_rn(248.0f, qh), 111.5f);
        float w = __fadd_rn(__fmul_rn(248.0f, qw), 111.5f);
        h = fminf(fmaxf(h, 0.0f), 223.0f);
        w = fminf(fmaxf(w, 0.0f), 223.0f);

        const float scl[4] = {0.25f, 0.125f, 0.0625f, 0.03125f}; // exact pow2
        const int   S[4]   = {56, 28, 14, 7};
        int r[4];
#pragma unroll
        for (int s = 0; s < 4; ++s) {
            float x = h * scl[s];
            float y = w * scl[s];
            int x1 = (int)floorf(x);
            int x2 = min((int)ceilf(x), S[s] - 1);
            int y1 = (int)floorf(y);
            int y2 = min((int)ceilf(y), S[s] - 1);
            int bit = (x2 - x1) * (y2 - y1);   // 0 or 1 (trunc==floor, x>=0)
            r[s] = bit ? (x1 * S[s] + y1) : -1;
        }
        idx4[n] = make_int4(r[0], r[1], r[2], r[3]);
    } else {
        // ---- feature transpose [C,H,W] -> [H*W, C] ----
        int d = (blk - 512) * 256 + threadIdx.x;   // < FT_TOTAL exactly
        int b = *batch;
        const float* src;
        int local, c, p, hw;
        if (d < 200704) {
            local = d;          c = local & 63;  p = local >> 6; hw = 3136;
            src = f0 + (size_t)b * 64 * 3136;
        } else if (d < 301056) {
            local = d - 200704; c = local & 127; p = local >> 7; hw = 784;
            src = f1 + (size_t)b * 128 * 784;
        } else if (d < 351232) {
            local = d - 301056; c = local & 255; p = local >> 8; hw = 196;
            src = f2 + (size_t)b * 256 * 196;
        } else {
            local = d - 351232; c = local & 511; p = local >> 9; hw = 49;
            src = f3 + (size_t)b * 512 * 49;
        }
        ft[d] = src[c * hw + p];   // scattered read (L2 absorbs), coalesced write
    }
}

// ------------------------------------------------------------------
// Kernel 2: the writer, ONE WAVE PER POINT. Lane i handles float4
// chunks {i, i+64, i+128, i+192} of the 240-chunk (960-float) row:
// every store instruction is a fully dense contiguous 1 KiB per wave,
// the idx int4 loads once per wave (uniform address -> broadcast),
// and the old per-thread gid/240 division disappears. ~2.5x fewer
// VALU per store keeps the CU front end feeding the store stream.
// Non-temporal: eviction hint keeps the 503 MB store stream from
// evicting the 1.44 MB transposed-feature working set.
// ------------------------------------------------------------------
__global__ __launch_bounds__(256) void k_gather(
    const int* __restrict__ idx,     // [N][4]
    const float* __restrict__ ft,    // transposed feats (L2-resident)
    float* __restrict__ out)         // [N, 960]
{
    const int lane = threadIdx.x & 63;
    const int n = blockIdx.x * 4 + (threadIdx.x >> 6);   // wave-uniform
    const int4 ids = *(const int4*)(idx + n * 4);        // broadcast 16B
    float* dst = out + (size_t)n * 960;

#pragma unroll
    for (int k = 0; k < 4; ++k) {
        int j = lane + k * 64;          // chunk index within the row
        if (j < 240) {                  // only masks lanes 48..63 at k=3
            int s  = (j >= 16) + (j >= 48) + (j >= 112);
            int id = (s == 0) ? ids.x : (s == 1) ? ids.y
                   : (s == 2) ? ids.z : ids.w;
            int C    = 64 << s;
            int toff = (s == 0) ? 0      : (s == 1) ? 200704
                     : (s == 2) ? 301056 : 351232;
            int jb   = (s == 0) ? 0 : (s == 1) ? 16 : (s == 2) ? 48 : 112;
            f32x4 v = (f32x4)(0.0f);
            if (id >= 0)
                v = *(const f32x4*)(ft + toff + id * C + (j - jb) * 4);
            __builtin_nontemporal_store(v, (f32x4*)(dst + j * 4));
        }
    }
}

extern "C" void kernel_launch(void* const* d_in, const int* in_sizes, int n_in,
                              void* d_out, int out_size, void* d_ws, size_t ws_size,
                              hipStream_t stream) {
    const float* f0  = (const float*)d_in[0];
    const float* f1  = (const float*)d_in[1];
    const float* f2  = (const float*)d_in[2];
    const float* f3  = (const float*)d_in[3];
    const float* pts = (const float*)d_in[4];
    const int* batch = (const int*)d_in[5];

    // ws layout: [ int4 idx[NPTS] : 2 MiB ][ f32 ft[FT_TOTAL] : 1.44 MiB ]
    int4* idx4 = (int4*)d_ws;
    float* ft = (float*)((char*)d_ws + (size_t)NPTS * 16);
    float* out = (float*)d_out;

    // 512 index blocks + 1470 transpose blocks, one launch
    k_prep<<<512 + 1470, 256, 0, stream>>>(pts, idx4, f0, f1, f2, f3, batch, ft);
    // one wave per point: 131072 points / 4 waves-per-block
    k_gather<<<NPTS / 4, 256, 0, stream>>>((const int*)idx4, ft, out);
}

// Round 2
// 497.628 us; speedup vs baseline: 1.0101x; 1.0101x over previous
//
#include <hip/hip_runtime.h>

#define NPTS 131072
// transposed feature region offsets (elements, fp32) in ws feature area:
//   scale0: 56*56*64 = 200704, scale1: 28*28*128 = 100352,
//   scale2: 14*14*256 = 50176, scale3: 7*7*512 = 25088  -> total 376320
#define FT_TOTAL 376320

typedef float f32x4 __attribute__((ext_vector_type(4)));

// ------------------------------------------------------------------
// Kernel 1 (fused prep): blocks [0,512) compute per-point projection
// indices (numerics IDENTICAL to the verified absmax==0.0 version);
// blocks [512,1982) transpose feat[b] [C,H,W] -> [H*W, C] so the
// per-point channel gather is contiguous. Both halves are exact
// multiples of 256 threads (131072 = 512*256, 376320 = 1470*256):
// no tail checks, block-uniform branch, one launch.
// ------------------------------------------------------------------
__global__ __launch_bounds__(256) void k_prep(
    const float* __restrict__ pts,
    int4* __restrict__ idx4,
    const float* __restrict__ f0,
    const float* __restrict__ f1,
    const float* __restrict__ f2,
    const float* __restrict__ f3,
    const int* __restrict__ batch,
    float* __restrict__ ft)
{
    int blk = blockIdx.x;
    if (blk < 512) {
        // ---- projection indices ----
        int n = blk * 256 + threadIdx.x;
        float px = pts[3 * n + 0];
        float py = pts[3 * n + 1];
        float pz = pts[3 * n + 2];
        float qh = __fdiv_rn(py, pz);
        float qw = __fdiv_rn(px, -pz);
        float h = __fadd_rn(__fmul_rn(248.0f, qh), 111.5f);
        float w = __fadd_rn(__fmul_rn(248.0f, qw), 111.5f);
        h = fminf(fmaxf(h, 0.0f), 223.0f);
        w = fminf(fmaxf(w, 0.0f), 223.0f);

        const float scl[4] = {0.25f, 0.125f, 0.0625f, 0.03125f}; // exact pow2
        const int   S[4]   = {56, 28, 14, 7};
        int r[4];
#pragma unroll
        for (int s = 0; s < 4; ++s) {
            float x = h * scl[s];
            float y = w * scl[s];
            int x1 = (int)floorf(x);
            int x2 = min((int)ceilf(x), S[s] - 1);
            int y1 = (int)floorf(y);
            int y2 = min((int)ceilf(y), S[s] - 1);
            int bit = (x2 - x1) * (y2 - y1);   // 0 or 1 (trunc==floor, x>=0)
            r[s] = bit ? (x1 * S[s] + y1) : -1;
        }
        idx4[n] = make_int4(r[0], r[1], r[2], r[3]);
    } else {
        // ---- feature transpose [C,H,W] -> [H*W, C] ----
        int d = (blk - 512) * 256 + threadIdx.x;   // < FT_TOTAL exactly
        int b = *batch;
        const float* src;
        int local, c, p, hw;
        if (d < 200704) {
            local = d;          c = local & 63;  p = local >> 6; hw = 3136;
            src = f0 + (size_t)b * 64 * 3136;
        } else if (d < 301056) {
            local = d - 200704; c = local & 127; p = local >> 7; hw = 784;
            src = f1 + (size_t)b * 128 * 784;
        } else if (d < 351232) {
            local = d - 301056; c = local & 255; p = local >> 8; hw = 196;
            src = f2 + (size_t)b * 256 * 196;
        } else {
            local = d - 351232; c = local & 511; p = local >> 9; hw = 49;
            src = f3 + (size_t)b * 512 * 49;
        }
        ft[d] = src[c * hw + p];   // scattered read (L2/L3 absorbs), coalesced write
    }
}

// ------------------------------------------------------------------
// Kernel 2: the writer. One thread = 4 output channels (one float4).
// 240 float4 per point; out address = gid*16 exactly -> the kernel's
// store stream is one perfectly linear 503 MB pass, one store per
// thread, no loop-carried dependency.
// A/B THIS ROUND: plain store (was __builtin_nontemporal_store).
// The NT hint was the only structural difference vs the 6.2 TB/s
// fillBuffer stream; ft protection in L2 is worth <1 us, so NT's only
// plausible net effect is throttling the store path.
// ------------------------------------------------------------------
__global__ __launch_bounds__(256) void k_gather(
    const int* __restrict__ idx,     // [N][4]
    const float* __restrict__ ft,    // transposed feats (L2-resident)
    float* __restrict__ out)         // [N, 960]
{
    int gid = blockIdx.x * 256 + threadIdx.x;  // total = N*240 exactly
    int n = gid / 240;                          // const div -> magic mul
    int j = gid - n * 240;                      // float4 chunk within row

    int s, C, toff, cb;
    if (j < 16)       { s = 0; C = 64;  toff = 0;      cb = j * 4; }
    else if (j < 48)  { s = 1; C = 128; toff = 200704; cb = (j - 16) * 4; }
    else if (j < 112) { s = 2; C = 256; toff = 301056; cb = (j - 48) * 4; }
    else              { s = 3; C = 512; toff = 351232; cb = (j - 112) * 4; }

    int id = idx[n * 4 + s];
    f32x4 v = (f32x4)(0.0f);
    if (id >= 0) {
        v = *(const f32x4*)(ft + toff + id * C + cb);  // coalesced L2 hit
    }
    *(f32x4*)(out + (size_t)n * 960 + j * 4) = v;      // plain, linear stream
}

extern "C" void kernel_launch(void* const* d_in, const int* in_sizes, int n_in,
                              void* d_out, int out_size, void* d_ws, size_t ws_size,
                              hipStream_t stream) {
    const float* f0  = (const float*)d_in[0];
    const float* f1  = (const float*)d_in[1];
    const float* f2  = (const float*)d_in[2];
    const float* f3  = (const float*)d_in[3];
    const float* pts = (const float*)d_in[4];
    const int* batch = (const int*)d_in[5];

    // ws layout: [ int4 idx[NPTS] : 2 MiB ][ f32 ft[FT_TOTAL] : 1.44 MiB ]
    int4* idx4 = (int4*)d_ws;
    float* ft = (float*)((char*)d_ws + (size_t)NPTS * 16);
    float* out = (float*)d_out;

    // 512 index blocks + 1470 transpose blocks, one launch
    k_prep<<<512 + 1470, 256, 0, stream>>>(pts, idx4, f0, f1, f2, f3, batch, ft);
    // N*240 / 256 = 122880 blocks exactly
    k_gather<<<122880, 256, 0, stream>>>((const int*)idx4, ft, out);
}